// Round 4
// baseline (365.966 us; speedup 1.0000x reference)
//
#include <hip/hip_runtime.h>

// NaturalVariation: out = x + softmax(x@W_sel + b_sel)@patterns + EMA(0.05*noise)
// B=4, T=8192, H=1024, P=8. fp32 in/out.
//
// EMA truncation: 0.9^64 = 1.18e-3 -> worst-case dropped tail ~3e-4 << tol.
// Chunks of 128 tokens are independent given a 64-step warm-up.
//
// R4 vs R3 (157us kernel):
//  - x-prefetch moved AFTER __syncthreads. R3 issued it before the barrier;
//    hipcc emits s_waitcnt vmcnt(0) before s_barrier, so the loads were
//    drained AT the barrier instead of hiding under softmax+phase2.
//  - phase-2 weight broadcast: 64 __shfl/subtile -> per-wave LDS buffer
//    (1 ds_write + 16 uniform ds_read_b128/subtile). Same-wave LDS is
//    pipe-ordered: no extra barrier.
//  - cross-wave reduce: pad stride 17->20 floats (16B aligned) so the
//    16-partial sum is 4x ds_read_b128 instead of 16x ds_read_b32.

#define T_LEN 8192
#define H_DIM 1024
#define B_DIM 4
#define NPAT 8
#define CHUNK 128            // tokens per block
#define SUB 8                // tokens per butterfly subtile
#define NSUB (CHUNK / SUB)   // 16
#define WARM 64              // EMA warm-up steps
#define NCHUNK (T_LEN / CHUNK)   // 64 chunks per batch row
#define RSTR 20              // LDS reduce stride in floats (80B: 16B-aligned)

static_assert(WARM <= CHUNK, "warm-up must stay within previous chunk");

// ---------------- Fused kernel ------------------------------------------
// grid = B*NCHUNK = 256 blocks of 1024 threads (16 waves; 1 block/CU).
__global__ __launch_bounds__(1024, 4) void kF_fused(
    const float* __restrict__ x, const float* __restrict__ noise,
    const float* __restrict__ Wsel, const float* __restrict__ bsel,
    const float* __restrict__ patterns, float* __restrict__ out)
{
    __shared__ float red[2][64 * RSTR];   // [buf][lane*RSTR + wave], 10.2KB
    __shared__ float wbuf[16][64];        // per-wave weights, 4KB

    const int tid  = threadIdx.x;
    const int wave = tid >> 6;            // 0..15
    const int lane = tid & 63;
    const int b    = blockIdx.x >> 6;     // / NCHUNK
    const int c    = blockIdx.x & (NCHUNK - 1);
    const size_t tokbase = (size_t)b * T_LEN + c * CHUNK;
    const int h    = tid;                 // this thread's column (0..1023)

    // Per-column constants (32KB W table + 32KB patterns: L1/L2 hot)
    const float4 wa = *(const float4*)(Wsel + (size_t)h * NPAT);
    const float4 wb = *(const float4*)(Wsel + (size_t)h * NPAT + 4);
    float pat[NPAT];
#pragma unroll
    for (int p = 0; p < NPAT; ++p) pat[p] = patterns[p * H_DIM + h];
    const float bs = bsel[lane & 7];      // bias of the slot this lane owns

    // EMA warm-up: 64 truncated-history steps (chunk 0 exact from t=0).
    float s = 0.0f;
    const int nw = (c == 0) ? 0 : WARM;
    const float* nptr = noise + (tokbase - nw) * (size_t)H_DIM + h;
#pragma unroll 8
    for (int i = 0; i < nw; ++i) {
        s = fmaf(0.9f, s, 0.005f * (*nptr));
        nptr += H_DIM;
    }
    // nptr now points at noise[tokbase][h]

    const float* xld = x + tokbase * H_DIM + h;   // x prefetch cursor
    float*       optr = out + tokbase * H_DIM + h;

    // prefetch subtile 0's x
    float xc[SUB];
#pragma unroll
    for (int j = 0; j < SUB; ++j)
        xc[j] = xld[(size_t)j * H_DIM];
    xld += (size_t)SUB * H_DIM;

#pragma unroll 2
    for (int st = 0; st < NSUB; ++st) {
        const int buf = st & 1;

        // ---- phase 1: stripe-partial logits for 8 tokens ----
        float a[64];
#pragma unroll
        for (int j = 0; j < SUB; ++j) {
            a[j * 8 + 0] = xc[j] * wa.x;
            a[j * 8 + 1] = xc[j] * wa.y;
            a[j * 8 + 2] = xc[j] * wa.z;
            a[j * 8 + 3] = xc[j] * wa.w;
            a[j * 8 + 4] = xc[j] * wb.x;
            a[j * 8 + 5] = xc[j] * wb.y;
            a[j * 8 + 6] = xc[j] * wb.z;
            a[j * 8 + 7] = xc[j] * wb.w;
        }
        // exchange-halves butterfly (R2-verified): after 6 steps, a[0] at
        // lane l = stripe sum for (token st*8 + (l>>3), pattern l&7)
#pragma unroll
        for (int sp = 0; sp < 6; ++sp) {
            const int o = 1 << sp;
            const int half = 32 >> sp;
            const bool hib = (lane & o) != 0;
#pragma unroll
            for (int m = 0; m < half; ++m) {
                const float lo = a[2 * m];
                const float hi = a[2 * m + 1];
                const float disc = hib ? lo : hi;
                const float keep = hib ? hi : lo;
                a[m] = keep + __shfl_xor(disc, o, 64);
            }
        }
        red[buf][lane * RSTR + wave] = a[0];

        __syncthreads();

        // ---- x-prefetch for next subtile: issued right AFTER the barrier
        // so it stays in flight under softmax + phase 2 (first use is next
        // subtile's phase 1, which precedes the next barrier).
        float xn[SUB];
        if (st + 1 < NSUB) {
#pragma unroll
            for (int j = 0; j < SUB; ++j)
                xn[j] = xld[(size_t)j * H_DIM];
            xld += (size_t)SUB * H_DIM;
        }

        // ---- cross-wave sum (redundant on all lanes) + softmax ----
        const float4* rp = (const float4*)(&red[buf][lane * RSTR]);
        float4 r0 = rp[0], r1 = rp[1], r2 = rp[2], r3 = rp[3];
        const float tot = ((r0.x + r0.y) + (r0.z + r0.w))
                        + ((r1.x + r1.y) + (r1.z + r1.w))
                        + ((r2.x + r2.y) + (r2.z + r2.w))
                        + ((r3.x + r3.y) + (r3.z + r3.w));
        const float logit = tot + bs;     // TEMPERATURE == 1.0

        // softmax across the 8 lanes sharing a token (R2-verified)
        float mx = logit;
        mx = fmaxf(mx, __shfl_xor(mx, 1, 64));
        mx = fmaxf(mx, __shfl_xor(mx, 2, 64));
        mx = fmaxf(mx, __shfl_xor(mx, 4, 64));
        const float e = __expf(logit - mx);
        float den = e;
        den += __shfl_xor(den, 1, 64);
        den += __shfl_xor(den, 2, 64);
        den += __shfl_xor(den, 4, 64);
        const float wgt = e / den;        // weight of (token l>>3, pat l&7)

        // per-wave weight buffer: same-wave LDS write->read is pipe-ordered
        wbuf[wave][lane] = wgt;

        // ---- phase 2: EMA + variation + store for the 8 tokens ----
#pragma unroll
        for (int j = 0; j < SUB; ++j) {
            const float4 wA = *(const float4*)(&wbuf[wave][j * 8]);
            const float4 wB = *(const float4*)(&wbuf[wave][j * 8 + 4]);

            const float nv = *nptr;
            s = fmaf(0.9f, s, 0.005f * nv);

            float v = 0.0f;
            v = fmaf(wA.x, pat[0], v);
            v = fmaf(wA.y, pat[1], v);
            v = fmaf(wA.z, pat[2], v);
            v = fmaf(wA.w, pat[3], v);
            v = fmaf(wB.x, pat[4], v);
            v = fmaf(wB.y, pat[5], v);
            v = fmaf(wB.z, pat[6], v);
            v = fmaf(wB.w, pat[7], v);

            *optr = xc[j] + v + s;
            nptr += H_DIM;
            optr += H_DIM;
        }

        // rotate prefetch buffer (register moves; waits resolved by now)
#pragma unroll
        for (int j = 0; j < SUB; ++j) xc[j] = xn[j];
    }
}

extern "C" void kernel_launch(void* const* d_in, const int* in_sizes, int n_in,
                              void* d_out, int out_size, void* d_ws, size_t ws_size,
                              hipStream_t stream) {
    const float* x        = (const float*)d_in[0];  // [B,T,H]
    const float* Wsel     = (const float*)d_in[1];  // [H,8]
    const float* bsel     = (const float*)d_in[2];  // [8]
    const float* patterns = (const float*)d_in[3];  // [8,H]
    const float* noise    = (const float*)d_in[4];  // [B,T,H]
    float* out = (float*)d_out;
    (void)d_ws; (void)ws_size;

    kF_fused<<<B_DIM * NCHUNK, 1024, 0, stream>>>(x, noise, Wsel, bsel,
                                                  patterns, out);
}

// Round 5
// 360.787 us; speedup vs baseline: 1.0144x; 1.0144x over previous
//
#include <hip/hip_runtime.h>

// NaturalVariation: out = x + softmax(x@W_sel + b_sel)@patterns + EMA(0.05*noise)
// B=4, T=8192, H=1024, P=8. fp32 in/out.
//
// EMA truncation: 0.9^64 = 1.18e-3 -> worst-case dropped tail ~3e-4 << tol.
// Chunks of 128 tokens are independent given a 64-step warm-up.
//
// R5: weights ONCE per chunk, not per 8-token subtile.
//   R3/R4 ran a 64-wide butterfly + barrier + softmax every 8 tokens
//   (16 barriers/chunk, ~600 VALU ops per subtile, 29-35% VALUBusy,
//   stuck at ~160us). New structure:
//   Part A (R2-kA verified wave algorithm): wave w computes weights for
//     tokens w*8..w*8+7 by accumulating over ALL H in registers (16 coalesced
//     r-iters), then ONE 63-step exchange-halves butterfly + 8-lane softmax.
//     Weights -> 4KB LDS. 16 waves x 8 tokens = the whole 128-token chunk.
//   ONE __syncthreads.
//   Part B (R1-kB verified streaming body, measured 3.1 TB/s): thread owns
//     column h=tid, 128 barrier-free iterations, uniform-LDS weight
//     broadcasts. x re-read hits LLC (Part A just fetched it; 128MB < 256MB).
//   Warm-up issued first so its 64 loads fly under Part A's FMA work.

#define T_LEN 8192
#define H_DIM 1024
#define B_DIM 4
#define NPAT 8
#define CHUNK 128            // tokens per block
#define WARM 64              // EMA warm-up steps
#define NCHUNK (T_LEN / CHUNK)   // 64 chunks per batch row

static_assert(WARM <= CHUNK, "warm-up must stay within previous chunk");

// grid = B*NCHUNK = 256 blocks of 1024 threads (16 waves/CU).
__global__ __launch_bounds__(1024, 4) void kF_fused(
    const float* __restrict__ x, const float* __restrict__ noise,
    const float* __restrict__ Wsel, const float* __restrict__ bsel,
    const float* __restrict__ patterns, float* __restrict__ out)
{
    __shared__ float wsm[CHUNK * NPAT];   // 4KB: chunk's softmax weights

    const int tid  = threadIdx.x;
    const int wave = tid >> 6;            // 0..15
    const int lane = tid & 63;
    const int b    = blockIdx.x >> 6;     // / NCHUNK
    const int c    = blockIdx.x & (NCHUNK - 1);
    const size_t tokbase = (size_t)b * T_LEN + c * CHUNK;
    const int h    = tid;                 // Part B column (0..1023)

    // ---- EMA warm-up first: loads in flight under Part A's FMA work ----
    float s = 0.0f;
    const int nw = (c == 0) ? 0 : WARM;
    const float* nptr = noise + (tokbase - nw) * (size_t)H_DIM + h;
#pragma unroll 8
    for (int i = 0; i < nw; ++i) {
        s = fmaf(0.9f, s, 0.005f * (*nptr));
        nptr += H_DIM;
    }
    // nptr now points at noise[tokbase][h]

    float pat[NPAT];
#pragma unroll
    for (int p = 0; p < NPAT; ++p) pat[p] = patterns[p * H_DIM + h];

    // ================= Part A: chunk weights (R2-kA algorithm) ==========
    // Wave w covers tokens tokbase + w*8 .. +7. Lane l sweeps columns
    // h = r*64 + l, accumulating 64 partials a[j*8+p] over all of H.
    {
        float a[64];
#pragma unroll
        for (int q = 0; q < 64; ++q) a[q] = 0.0f;

        const float* xw = x + (tokbase + (size_t)wave * 8) * H_DIM + lane;

#pragma unroll 2
        for (int r = 0; r < 16; ++r) {
            const int hh = r * 64 + lane;
            // W row: 8 floats at 32B lane stride -> 2KB span, fully used
            const float4 wa = *(const float4*)(Wsel + (size_t)hh * NPAT);
            const float4 wb = *(const float4*)(Wsel + (size_t)hh * NPAT + 4);
            float xv[8];
#pragma unroll
            for (int j = 0; j < 8; ++j)        // 256B/wave coalesced
                xv[j] = xw[(size_t)j * H_DIM + r * 64];
#pragma unroll
            for (int j = 0; j < 8; ++j) {
                a[j * 8 + 0] = fmaf(xv[j], wa.x, a[j * 8 + 0]);
                a[j * 8 + 1] = fmaf(xv[j], wa.y, a[j * 8 + 1]);
                a[j * 8 + 2] = fmaf(xv[j], wa.z, a[j * 8 + 2]);
                a[j * 8 + 3] = fmaf(xv[j], wa.w, a[j * 8 + 3]);
                a[j * 8 + 4] = fmaf(xv[j], wb.x, a[j * 8 + 4]);
                a[j * 8 + 5] = fmaf(xv[j], wb.y, a[j * 8 + 5]);
                a[j * 8 + 6] = fmaf(xv[j], wb.z, a[j * 8 + 6]);
                a[j * 8 + 7] = fmaf(xv[j], wb.w, a[j * 8 + 7]);
            }
        }

        // ONE exchange-halves butterfly (R2-verified): 63 shfl+add total.
        // After 6 steps, a[0] at lane l = logit partial-free full sum for
        // (token wave*8 + (l>>3), pattern l&7).
#pragma unroll
        for (int sp = 0; sp < 6; ++sp) {
            const int o = 1 << sp;
            const int half = 32 >> sp;
            const bool hib = (lane & o) != 0;
#pragma unroll
            for (int m = 0; m < half; ++m) {
                const float lo = a[2 * m];
                const float hi = a[2 * m + 1];
                const float disc = hib ? lo : hi;
                const float keep = hib ? hi : lo;
                a[m] = keep + __shfl_xor(disc, o, 64);
            }
        }

        const float logit = a[0] + bsel[lane & 7];   // TEMPERATURE == 1.0

        // softmax across the 8 lanes sharing a token (R2-verified)
        float mx = logit;
        mx = fmaxf(mx, __shfl_xor(mx, 1, 64));
        mx = fmaxf(mx, __shfl_xor(mx, 2, 64));
        mx = fmaxf(mx, __shfl_xor(mx, 4, 64));
        const float e = __expf(logit - mx);
        float den = e;
        den += __shfl_xor(den, 1, 64);
        den += __shfl_xor(den, 2, 64);
        den += __shfl_xor(den, 4, 64);

        // wsm[(w*8 + l>>3)*8 + (l&7)] == wsm[w*64 + l]: coalesced, 2-way max
        wsm[wave * 64 + lane] = e / den;
    }

    __syncthreads();   // the ONLY barrier

    // ================= Part B: streaming fuse (R1-kB body) ==============
    // Thread owns column h. x re-read comes from LLC (Part A fetched it).
    const float* xptr = x + tokbase * H_DIM + h;
    float*       optr = out + tokbase * H_DIM + h;
#pragma unroll 8
    for (int i = 0; i < CHUNK; ++i) {
        const float nv = *nptr;
        const float xv = *xptr;
        s = fmaf(0.9f, s, 0.005f * nv);

        // uniform-address LDS reads (broadcast, conflict-free)
        const float4 wA = *(const float4*)(wsm + i * NPAT);
        const float4 wB = *(const float4*)(wsm + i * NPAT + 4);
        float v = 0.0f;
        v = fmaf(wA.x, pat[0], v);
        v = fmaf(wA.y, pat[1], v);
        v = fmaf(wA.z, pat[2], v);
        v = fmaf(wA.w, pat[3], v);
        v = fmaf(wB.x, pat[4], v);
        v = fmaf(wB.y, pat[5], v);
        v = fmaf(wB.z, pat[6], v);
        v = fmaf(wB.w, pat[7], v);

        *optr = xv + v + s;
        nptr += H_DIM; xptr += H_DIM; optr += H_DIM;
    }
}

extern "C" void kernel_launch(void* const* d_in, const int* in_sizes, int n_in,
                              void* d_out, int out_size, void* d_ws, size_t ws_size,
                              hipStream_t stream) {
    const float* x        = (const float*)d_in[0];  // [B,T,H]
    const float* Wsel     = (const float*)d_in[1];  // [H,8]
    const float* bsel     = (const float*)d_in[2];  // [8]
    const float* patterns = (const float*)d_in[3];  // [8,H]
    const float* noise    = (const float*)d_in[4];  // [B,T,H]
    float* out = (float*)d_out;
    (void)d_ws; (void)ws_size;

    kF_fused<<<B_DIM * NCHUNK, 1024, 0, stream>>>(x, noise, Wsel, bsel,
                                                  patterns, out);
}